// Round 1
// 300.880 us; speedup vs baseline: 1.0286x; 1.0286x over previous
//
#include <hip/hip_runtime.h>
#include <math.h>

// Problem constants
#define NCELLS 131072
#define IND 64
#define HD 128
#define OUTD 64
#define NF 8
#define FS 16384
#define DC 4096
#define TB 64             // cells per fused block
#define NBLK (NCELLS/TB)  // 2048
#define NTH 512

typedef __bf16 bf16x8 __attribute__((ext_vector_type(8)));
typedef float f32x4 __attribute__((ext_vector_type(4)));
typedef unsigned short us8 __attribute__((ext_vector_type(8)));

#define MFMA(a,b,c) __builtin_amdgcn_mfma_f32_16x16x32_bf16(a,b,c,0,0,0)

// ---- workspace layout ----
// ushort (bf16) region:
#define WS_W1H 0          // [256][128]  h-part of fused [W1a;W1g] (x-part folded into bias)
#define WS_W2F 32768      // [64][256]   fused [W2a | -W2g]
#define WS_WIH 49152      // [384][64]   Wih out-columns only (t-col handled in fp32)
#define WS_WHH 73728      // [384][128]
#define WS_U_TOTAL 122880
// float region at (float*)((ushort*)ws + WS_U_TOTAL):
#define WF_B1   0         // [256] = b1 + x @ W1x.T   (fp32 exact fold)
#define WF_B2   256       // [64]
#define WF_WT   320       // [384] = Wih[:,64] fp32 (t-column)
#define WF_FSUM 704       // [8][128]
#define WF_WSUM 1728      // [64]
#define WF_SE   1792
#define WF_TS   1793
#define WF_TOTAL 1796
// aligned newh scratch (fp32) at byte offset: align256(122880*2 + 1796*4 = 252944)
#define WS_NH_OFF 253184

// ---- LDS layout (ushort units), total 25600 us = 51200 B -> 3 blocks/CU ----
// sof/sob/st/se/wscr overlay the dead sh1 region after phase 2's reads complete.
#define L_SC    0         // [64][136] us : h bf16 (stride 272B, 16B-aligned rows)
#define L_SH1   8704      // [64][264] us : relu(h1) bf16
#define L_SOF_F 4352      // float idx (us 8704): [64][68] f32 out
#define L_SOB   17408     // [64][72] us : out bf16 (stride 144B, 16B-aligned)
#define L_ST_F  11008     // us 22016: [64] f32 t
#define L_SE_F  11072     // us 22144: [64] f32 e^t
#define L_WSCR_F 11136    // us 22272: [512] f32 reduction scratch
#define L_TOT   25600

__device__ __forceinline__ unsigned short f2bf(float f) {
    unsigned u = __builtin_bit_cast(unsigned, f);
    return (unsigned short)((u + 0x7FFFu + ((u >> 16) & 1u)) >> 16);
}
__device__ __forceinline__ float bf2f(unsigned short h) {
    return __builtin_bit_cast(float, (unsigned)h << 16);
}
__device__ __forceinline__ bf16x8 ld8(const unsigned short* p) {
    return __builtin_bit_cast(bf16x8, *(const us8*)p);
}
// fast activations: v_exp_f32 + v_rcp_f32 (~1 ulp each; tolerance budget ~0.009)
__device__ __forceinline__ float sigm(float v) {
    return __builtin_amdgcn_rcpf(1.f + __builtin_amdgcn_exp2f(-1.44269504f * v));
}
__device__ __forceinline__ float tanh_fast(float v) {
    return 1.f - 2.f * __builtin_amdgcn_rcpf(1.f + __builtin_amdgcn_exp2f(2.88539008f * v));
}

// ---- per-launch weight conversion fp32 -> bf16 (+ fp32 bias folds) ----
__global__ __launch_bounds__(256) void convert_kernel(
    const float* __restrict__ x,
    const float* __restrict__ W1a, const float* __restrict__ b1a,
    const float* __restrict__ W2a, const float* __restrict__ b2a,
    const float* __restrict__ W1g, const float* __restrict__ b1g,
    const float* __restrict__ W2g, const float* __restrict__ b2g,
    const float* __restrict__ Wih, const float* __restrict__ Whh,
    unsigned short* __restrict__ wsu, float* __restrict__ wsf)
{
    int i = blockIdx.x * 256 + threadIdx.x;
    if (i < 32768) {                         // W1H [256][128] from c-cols 64..191
        int r = i >> 7, k = i & 127;
        float v = (r < 128) ? W1a[r*192 + 64 + k] : W1g[(r-128)*192 + 64 + k];
        wsu[WS_W1H + i] = f2bf(v); return;
    }
    int j = i - 32768;
    if (j < 16384) {                         // W2F [64][256]
        int r = j >> 8, k = j & 255;
        float v = (k < 128) ? W2a[r*128 + k] : -W2g[r*128 + (k-128)];
        wsu[WS_W2F + j] = f2bf(v); return;
    }
    j -= 16384;
    if (j < 24576) {                         // WIH [384][64] (drop t-col)
        int r = j >> 6, k = j & 63;
        wsu[WS_WIH + j] = f2bf(Wih[r*65 + k]); return;
    }
    j -= 24576;
    if (j < 49152) { wsu[WS_WHH + j] = f2bf(Whh[j]); return; }
    j -= 49152;
    if (j < 256) {                           // b1' = b1 + x @ W1x.T  (fp32)
        const float* wr = (j < 128) ? (W1a + j*192) : (W1g + (size_t)(j-128)*192);
        float base = (j < 128) ? b1a[j] : b1g[j-128];
        float dot = 0.f;
        #pragma unroll 8
        for (int k = 0; k < 64; ++k) dot += x[k] * wr[k];
        wsf[WF_B1 + j] = base + dot; return;
    }
    j -= 256;
    if (j < 64)  { wsf[WF_B2 + j] = b2a[j] - b2g[j]; return; }
    j -= 64;
    if (j < 384) { wsf[WF_WT + j] = Wih[j*65 + 64]; return; }
}

// ---- fused per-cell pipeline, bf16 MFMA, TB=64, 8 waves ----
__global__ __launch_bounds__(NTH, 8) void fused_cell_kernel(
    const float* __restrict__ hiddens,
    const float* __restrict__ bih, const float* __restrict__ bhh,
    const unsigned short* __restrict__ wsu, const float* __restrict__ wsf,
    float* __restrict__ newh, float* __restrict__ fsum,
    float* __restrict__ wsum, float* __restrict__ sumexp, float* __restrict__ tsum)
{
    __shared__ __align__(16) unsigned short sm[L_TOT];
    float* smf = (float*)sm;

    const int tid = threadIdx.x;
    const int cell0 = blockIdx.x * TB;
    const int w = tid >> 6, lane = tid & 63;
    const int q = lane >> 4, cL = lane & 15;

    // ---- phase 0: stage h bf16 into sc [64][136] ----
    for (int idx = tid; idx < TB*(HD/4); idx += NTH) {
        int c = idx >> 5, k4 = idx & 31;
        float4 v = ((const float4*)hiddens)[(size_t)(cell0+c)*(HD/4) + k4];
        unsigned p0 = (unsigned)f2bf(v.x) | ((unsigned)f2bf(v.y) << 16);
        unsigned p1 = (unsigned)f2bf(v.z) | ((unsigned)f2bf(v.w) << 16);
        *(unsigned*)&sm[L_SC + c*136 + k4*4]     = p0;
        *(unsigned*)&sm[L_SC + c*136 + k4*4 + 2] = p1;
    }
    __syncthreads();

    // ---- phase 1: GEMM1  h1 = relu(h @ W1h.T + b1'), K=128, cols 256 ----
    #pragma unroll
    for (int ct = 0; ct < 2; ++ct) {
        const int col = w*32 + ct*16 + cL;
        const float bias = wsf[WF_B1 + col];
        f32x4 acc[4];
        #pragma unroll
        for (int m = 0; m < 4; ++m) acc[m] = (f32x4){bias,bias,bias,bias};
        const unsigned short* wp = wsu + WS_W1H + col*128 + q*8;
        #pragma unroll
        for (int k = 0; k < 4; ++k) {
            bf16x8 B = ld8(wp + k*32);
            #pragma unroll
            for (int m = 0; m < 4; ++m) {
                bf16x8 A = ld8(&sm[L_SC + (m*16+cL)*136 + k*32 + q*8]);
                acc[m] = MFMA(A, B, acc[m]);
            }
        }
        #pragma unroll
        for (int m = 0; m < 4; ++m)
            #pragma unroll
            for (int r = 0; r < 4; ++r)
                sm[L_SH1 + (m*16+q*4+r)*264 + col] = f2bf(fmaxf(acc[m][r], 0.f));
    }
    __syncthreads();

    // ---- phase 2: GEMM2  out = h1 @ W2f.T + b2f ----
    f32x4 o0, o1;
    {
        const int col = (w & 3)*16 + cL;
        const int Mt0 = (w >> 2)*2, Mt1 = Mt0 + 1;
        const float bias = wsf[WF_B2 + col];
        o0 = (f32x4){bias,bias,bias,bias}; o1 = o0;
        const unsigned short* wp = wsu + WS_W2F + col*256 + q*8;
        #pragma unroll
        for (int k = 0; k < 8; ++k) {
            bf16x8 B  = ld8(wp + k*32);
            bf16x8 A0 = ld8(&sm[L_SH1 + (Mt0*16+cL)*264 + k*32 + q*8]);
            o0 = MFMA(A0, B, o0);
            bf16x8 A1 = ld8(&sm[L_SH1 + (Mt1*16+cL)*264 + k*32 + q*8]);
            o1 = MFMA(A1, B, o1);
        }
    }
    __syncthreads();   // all sh1 reads done; overlay region now writable

    // ---- phase 2b: out tiles into overlay (sof fp32, sob bf16) ----
    {
        const int col = (w & 3)*16 + cL;
        const int Mt0 = (w >> 2)*2, Mt1 = Mt0 + 1;
        #pragma unroll
        for (int r = 0; r < 4; ++r) {
            int r0 = Mt0*16 + q*4 + r, r1 = Mt1*16 + q*4 + r;
            smf[L_SOF_F + r0*68 + col] = o0[r];
            sm [L_SOB   + r0*72 + col] = f2bf(o0[r]);
            smf[L_SOF_F + r1*68 + col] = o1[r];
            sm [L_SOB   + r1*72 + col] = f2bf(o1[r]);
        }
    }
    __syncthreads();

    // ---- phase 3: t = mean(out^2), e^t  (all 512 threads; 8 lanes per cell) ----
    {
        const int c = tid >> 3, g = tid & 7;
        f32x4 a = *(const f32x4*)&smf[L_SOF_F + c*68 + g*8];
        f32x4 b = *(const f32x4*)&smf[L_SOF_F + c*68 + g*8 + 4];
        float s = a[0]*a[0] + a[1]*a[1] + a[2]*a[2] + a[3]*a[3]
                + b[0]*b[0] + b[1]*b[1] + b[2]*b[2] + b[3]*b[3];
        s += __shfl_xor(s, 1);
        s += __shfl_xor(s, 2);
        s += __shfl_xor(s, 4);
        if (g == 0) {
            float t = s * (1.0f/OUTD);
            smf[L_ST_F + c] = t;
            smf[L_SE_F + c] = __builtin_amdgcn_exp2f(t * 1.44269504f);
        }
    }
    __syncthreads();

    // ---- phase 4: GRU gates (MFMA K=64 gi + K=128 gh; t as fp32 rank-1 fix) ----
    const int fidx = (int)(blockIdx.x >> 8);     // 256 blocks per faction
    {
        const int j = w*16 + cL;                 // hidden unit for this lane
        const float bR = bih[j]      + bhh[j];
        const float bZ = bih[HD+j]   + bhh[HD+j];
        const float bI = bih[2*HD+j];
        const float bH = bhh[2*HD+j];
        const float wtR = wsf[WF_WT + j];
        const float wtZ = wsf[WF_WT + HD + j];
        const float wtI = wsf[WF_WT + 2*HD + j];
        const unsigned short* wi = wsu + WS_WIH + j*64  + q*8;
        const unsigned short* wh = wsu + WS_WHH + j*128 + q*8;
        float colsum = 0.f;
        #pragma unroll
        for (int half = 0; half < 2; ++half) {
            const int Mt0 = half*2, Mt1 = Mt0 + 1;
            f32x4 R0 = {bR,bR,bR,bR}, R1 = R0;
            f32x4 Z0 = {bZ,bZ,bZ,bZ}, Z1 = Z0;
            f32x4 I0 = {bI,bI,bI,bI}, I1 = I0;
            f32x4 H0 = {bH,bH,bH,bH}, H1 = H0;
            #pragma unroll
            for (int k = 0; k < 2; ++k) {        // gi: K=64 (out only)
                bf16x8 Br = ld8(wi + k*32);
                bf16x8 Bz = ld8(wi + HD*64 + k*32);
                bf16x8 Bi = ld8(wi + 2*HD*64 + k*32);
                bf16x8 A0 = ld8(&sm[L_SOB + (Mt0*16+cL)*72 + k*32 + q*8]);
                bf16x8 A1 = ld8(&sm[L_SOB + (Mt1*16+cL)*72 + k*32 + q*8]);
                R0 = MFMA(A0, Br, R0); R1 = MFMA(A1, Br, R1);
                Z0 = MFMA(A0, Bz, Z0); Z1 = MFMA(A1, Bz, Z1);
                I0 = MFMA(A0, Bi, I0); I1 = MFMA(A1, Bi, I1);
            }
            #pragma unroll
            for (int k = 0; k < 4; ++k) {        // gh: K=128
                bf16x8 Br = ld8(wh + k*32);
                bf16x8 Bz = ld8(wh + HD*128 + k*32);
                bf16x8 Bn = ld8(wh + 2*HD*128 + k*32);
                bf16x8 A0 = ld8(&sm[L_SC + (Mt0*16+cL)*136 + k*32 + q*8]);
                bf16x8 A1 = ld8(&sm[L_SC + (Mt1*16+cL)*136 + k*32 + q*8]);
                R0 = MFMA(A0, Br, R0); R1 = MFMA(A1, Br, R1);
                Z0 = MFMA(A0, Bz, Z0); Z1 = MFMA(A1, Bz, Z1);
                H0 = MFMA(A0, Bn, H0); H1 = MFMA(A1, Bn, H1);
            }
            #pragma unroll
            for (int r = 0; r < 4; ++r) {
                const int row = Mt0*16 + q*4 + r;
                const float tv = smf[L_ST_F + row];
                const float rr = sigm(R0[r] + tv*wtR);
                const float zz = sigm(Z0[r] + tv*wtZ);
                const float nn = tanh_fast(I0[r] + tv*wtI + rr*H0[r]);
                const float hold = bf2f(sm[L_SC + row*136 + j]);
                const float hv = (1.f - zz)*nn + zz*hold;
                newh[(size_t)(cell0+row)*HD + j] = hv;
                colsum += hv;
            }
            #pragma unroll
            for (int r = 0; r < 4; ++r) {
                const int row = Mt1*16 + q*4 + r;
                const float tv = smf[L_ST_F + row];
                const float rr = sigm(R1[r] + tv*wtR);
                const float zz = sigm(Z1[r] + tv*wtZ);
                const float nn = tanh_fast(I1[r] + tv*wtI + rr*H1[r]);
                const float hold = bf2f(sm[L_SC + row*136 + j]);
                const float hv = (1.f - zz)*nn + zz*hold;
                newh[(size_t)(cell0+row)*HD + j] = hv;
                colsum += hv;
            }
        }
        colsum += __shfl_xor(colsum, 16);
        colsum += __shfl_xor(colsum, 32);
        if (q == 0) unsafeAtomicAdd(&fsum[fidx*HD + j], colsum);
    }

    // ---- phase 5: softmax-weighted sums, parallel across all 8 waves ----
    {
        const int col = tid & 63, cg = tid >> 6;
        float wacc = 0.f;
        #pragma unroll
        for (int c8 = 0; c8 < 8; ++c8) {
            const int c = cg*8 + c8;
            wacc += smf[L_SE_F + c] * smf[L_SOF_F + c*68 + col];
        }
        smf[L_WSCR_F + cg*64 + col] = wacc;
    }
    __syncthreads();
    if (tid < 64) {
        float wacc = 0.f;
        #pragma unroll
        for (int g = 0; g < 8; ++g) wacc += smf[L_WSCR_F + g*64 + tid];
        unsafeAtomicAdd(&wsum[tid], wacc);
        float e = smf[L_SE_F + tid];
        float t = smf[L_ST_F + tid];
        #pragma unroll
        for (int d = 1; d < 64; d <<= 1) { e += __shfl_xor(e, d); t += __shfl_xor(t, d); }
        if (tid == 0) { unsafeAtomicAdd(sumexp, e); unsafeAtomicAdd(tsum, t); }
    }
}

// ---- faction sync: dst = a*src + b[j]; block 0 also computes the pred head ----
#define TBF 64
__global__ __launch_bounds__(256) void faction_kernel(
    const float* __restrict__ src, float* __restrict__ dst,
    const float* __restrict__ fsum, const int* __restrict__ step,
    const float* __restrict__ Wo, const float* __restrict__ bo,
    const float* __restrict__ wsum, const float* __restrict__ sumexp,
    const float* __restrict__ tsum, float* __restrict__ d_out)
{
    __shared__ float bnon[HD], bdeb[HD];
    const int cell0 = blockIdx.x * TBF;
    const int f = blockIdx.x >> 8;            // 256 blocks per faction
    if (threadIdx.x < HD) {
        const int jc = threadIdx.x;
        float s = 0.f;
        #pragma unroll
        for (int ff = 0; ff < NF; ++ff) s += fsum[ff*HD + jc];
        const float go = s * (1.0f/NCELLS);
        const float fm = fsum[f*HD + jc] * (1.0f/FS);
        bnon[jc] = 0.15f*fm;
        bdeb[jc] = 0.1275f*fm + 0.15f*go;
    }
    __syncthreads();
    const bool debate = (step[0] > 5) && ((cell0 & (FS-1)) < DC);  // uniform per block
    const float a = debate ? 0.7225f : 0.85f;
    const float* brow = debate ? bdeb : bnon;
    #pragma unroll
    for (int i = 0; i < (TBF*HD)/256; ++i) {   // dst possibly 4B-aligned only -> scalar
        const int idx = threadIdx.x + i*256;
        const int j = idx & 127;
        const size_t e = (size_t)cell0*HD + idx;
        dst[e] = a*src[e] + brow[j];
    }
    if (blockIdx.x == 0 && threadIdx.x < OUTD) {  // fused final head (saves a launch)
        const int i = threadIdx.x;
        const float inv = 1.0f / sumexp[0];
        const float* wr = Wo + (size_t)i*OUTD;
        float acc = bo[i];
        #pragma unroll 8
        for (int jj = 0; jj < OUTD; ++jj) acc += (wsum[jj]*inv) * wr[jj];
        d_out[i] = acc;
        if (i == 0) d_out[OUTD] = tsum[0] * (1.0f/NCELLS);
    }
}

extern "C" void kernel_launch(void* const* d_in, const int* in_sizes, int n_in,
                              void* d_out, int out_size, void* d_ws, size_t ws_size,
                              hipStream_t stream)
{
    const float* x   = (const float*)d_in[0];
    const float* hid = (const float*)d_in[1];
    const float* W1a = (const float*)d_in[2];
    const float* b1a = (const float*)d_in[3];
    const float* W2a = (const float*)d_in[4];
    const float* b2a = (const float*)d_in[5];
    const float* W1g = (const float*)d_in[6];
    const float* b1g = (const float*)d_in[7];
    const float* W2g = (const float*)d_in[8];
    const float* b2g = (const float*)d_in[9];
    const float* Wih = (const float*)d_in[10];
    const float* Whh = (const float*)d_in[11];
    const float* bih = (const float*)d_in[12];
    const float* bhh = (const float*)d_in[13];
    const float* Wo  = (const float*)d_in[14];
    const float* bo  = (const float*)d_in[15];
    const int*  step = (const int*)d_in[16];

    float* out  = (float*)d_out;
    float* newh_out = out + (OUTD + 1);

    unsigned short* wsu = (unsigned short*)d_ws;
    float* wsf = (float*)(wsu + WS_U_TOTAL);
    float* fsum   = wsf + WF_FSUM;
    float* wsum   = wsf + WF_WSUM;
    float* sumexp = wsf + WF_SE;
    float* tsum   = wsf + WF_TS;

    // aligned pre-sync newh scratch if workspace allows; else in-place in d_out
    const size_t need = (size_t)WS_NH_OFF + (size_t)NCELLS*HD*sizeof(float);
    float* nh_store = (ws_size >= need) ? (float*)((char*)d_ws + WS_NH_OFF) : newh_out;

    hipMemsetAsync(fsum, 0, (NF*HD + OUTD + 2)*sizeof(float), stream);

    // total convert elements: 32768+16384+24576+49152+256+64+384 = 123584
    convert_kernel<<<(123584 + 255)/256, 256, 0, stream>>>(
        x, W1a, b1a, W2a, b2a, W1g, b1g, W2g, b2g, Wih, Whh, wsu, wsf);

    fused_cell_kernel<<<NBLK, NTH, 0, stream>>>(
        hid, bih, bhh, wsu, wsf, nh_store, fsum, wsum, sumexp, tsum);

    faction_kernel<<<NCELLS/TBF, 256, 0, stream>>>(
        nh_store, newh_out, fsum, step, Wo, bo, wsum, sumexp, tsum, out);
}